// Round 1
// baseline (240.530 us; speedup 1.0000x reference)
//
#include <hip/hip_runtime.h>
#include <hip/hip_bf16.h>

typedef __attribute__((ext_vector_type(8))) short bf16x8;
typedef __attribute__((ext_vector_type(4))) float f32x4;

#define LOG2E 1.44269504088896340736f

// ---- workspace layout ----
// bf16 element offsets
#define XQ_OFF 0
#define XK_OFF 524288
#define XV_OFF 1048576
#define WQ_OFF 1572864
#define WK_OFF 1835008
#define WV_OFF 2097152
#define WO_OFF 2359296
#define QB_OFF 2621440
#define KB_OFF 3145728
#define VT_OFF 3670016
#define AO_OFF 4194304
// byte offsets (fp32 tables / seg indices)
#define T_B   9437184
#define A_B   (T_B + 4096)
#define C_B   (A_B + 20480)
#define SEG_B (C_B + 20480)

__device__ __forceinline__ unsigned short f2bf(float f) {
  union { __hip_bfloat16 h; unsigned short u; } c;
  c.h = __float2bfloat16(f);
  return c.u;
}

// ---------------- fp32 -> bf16 convert; weights transposed [k][n] -> [n][k] ----------------
__global__ __launch_bounds__(256) void k_convert(
    const float* __restrict__ xq, const float* __restrict__ xk, const float* __restrict__ xv,
    const float* __restrict__ wq, const float* __restrict__ wk, const float* __restrict__ wv,
    const float* __restrict__ wo, unsigned short* __restrict__ wsb) {
  int i = blockIdx.x * 256 + threadIdx.x;  // one float4 per thread; 655360 total
  if (i < 393216) {                        // xq/xk/xv plain: 3 x 131072 float4
    int region = i >> 17;
    int off = i & 131071;
    const float* src = (region == 0) ? xq : (region == 1) ? xk : xv;
    float4 v = ((const float4*)src)[off];
    ushort4 o;
    o.x = f2bf(v.x); o.y = f2bf(v.y); o.z = f2bf(v.z); o.w = f2bf(v.w);
    ((ushort4*)wsb)[i] = o;
  } else {                                 // W's transposed: 4 x 65536 float4
    int j = i - 393216;
    int region = j >> 16;
    int off = j & 65535;
    const float* src = (region == 0) ? wq : (region == 1) ? wk : (region == 2) ? wv : wo;
    float4 v = ((const float4*)src)[off];
    int flat = off << 2;
    int k = flat >> 9, n = flat & 511;
    unsigned short* dst = wsb + WQ_OFF + region * 262144;
    dst[(n + 0) * 512 + k] = f2bf(v.x);
    dst[(n + 1) * 512 + k] = f2bf(v.y);
    dst[(n + 2) * 512 + k] = f2bf(v.z);
    dst[(n + 3) * 512 + k] = f2bf(v.w);
  }
}

// ---------------- edge MLP -> exact piecewise-linear tables ----------------
// f_h(e) = sum_k We2[k,h]*relu(e*w1[k]+b1[k]) + be2[h]  is PWL with breakpoints t_k=-b1/w1.
// Sort breakpoints; per segment s in [0,512]: f_h(e) = A[s][h]*e + C[s][h].
__global__ __launch_bounds__(512) void k_prep(
    const float* __restrict__ w1, const float* __restrict__ b1,
    const float* __restrict__ we2, const float* __restrict__ be2,
    float* __restrict__ wsT, float* __restrict__ wsA, float* __restrict__ wsC) {
  __shared__ float sT[512];
  __shared__ int sIdx[512];
  __shared__ float sDA[512][8];
  __shared__ float sDC[512][8];
  int tid = threadIdx.x;
  {
    float w = w1[tid], bb = b1[tid];
    sT[tid] = (w != 0.f) ? (-bb / w) : -3.4e38f;  // w==0: never a real crossing
    sIdx[tid] = tid;
  }
  // bitonic sort ascending (512 elems, 512 threads)
  for (int size = 2; size <= 512; size <<= 1) {
    for (int stride = size >> 1; stride > 0; stride >>= 1) {
      __syncthreads();
      int i = tid, j = tid ^ stride;
      if (j > i) {
        bool up = ((i & size) == 0);
        float ti = sT[i], tj = sT[j];
        if (up ? (ti > tj) : (ti < tj)) {
          sT[i] = tj; sT[j] = ti;
          int t = sIdx[i]; sIdx[i] = sIdx[j]; sIdx[j] = t;
        }
      }
    }
  }
  __syncthreads();
  wsT[tid] = sT[tid];
  {
    int k = sIdx[tid];
    float wk = w1[k], bk = b1[k];
    for (int h = 0; h < 8; ++h) {
      float w2 = we2[k * 8 + h];
      float da = 0.f, dc = 0.f;
      if (wk > 0.f)      { da =  w2 * wk; dc =  w2 * bk; }  // activates crossing upward
      else if (wk < 0.f) { da = -w2 * wk; dc = -w2 * bk; }  // deactivates
      sDA[tid][h] = da; sDC[tid][h] = dc;
    }
  }
  __syncthreads();
  if (tid < 8) {
    int h = tid;
    // segment 0 (e below all breakpoints): active set = {k : w1[k] < 0}
    float a = 0.f, c = be2[h];
    for (int k = 0; k < 512; ++k) {
      float wk = w1[k], bk = b1[k], w2 = we2[k * 8 + h];
      if (wk < 0.f)       { a += w2 * wk; c += w2 * bk; }
      else if (wk == 0.f) { c += w2 * fmaxf(bk, 0.f); }
    }
    wsA[h] = a; wsC[h] = c;
    for (int s = 0; s < 512; ++s) {
      a += sDA[s][h]; c += sDC[s][h];
      wsA[(s + 1) * 8 + h] = a;
      wsC[(s + 1) * 8 + h] = c;
    }
  }
}

// ---------------- per-edge segment index (shared by all 8 heads) ----------------
__global__ __launch_bounds__(256) void k_seg(const float* __restrict__ eg,
                                             const float* __restrict__ wsT,
                                             unsigned short* __restrict__ segp) {
  __shared__ float sT[512];
  int tid = threadIdx.x;
  sT[tid] = wsT[tid];
  sT[tid + 256] = wsT[tid + 256];
  __syncthreads();
  int i = blockIdx.x * 256 + tid;  // 524288 total
  float ev = eg[i];
  int lo = 0, hi = 512;
  while (lo < hi) {  // count of T[s] < ev (exact at ties: relu(0)=0 both sides)
    int mid = (lo + hi) >> 1;
    if (sT[mid] < ev) lo = mid + 1; else hi = mid;
  }
  segp[i] = (unsigned short)lo;
}

// ---------------- bf16 MFMA GEMM: Y = X @ W + bias, M=1024 N=512 K=512 ----------------
struct GemmBatch {
  const unsigned short* A;   // [M][K] bf16
  const unsigned short* Wt;  // [N][K] bf16 (pre-transposed weight)
  const float* bias;         // [N] fp32
  void* out;
  int mode;  // 0: bf16 [b,h,l,d]; 1: fp32 row-major [m][n]; 2: bf16 [b,h,d,l] (V transposed)
};

__global__ __launch_bounds__(256) void k_gemm(GemmBatch g0, GemmBatch g1, GemmBatch g2) {
  GemmBatch g = (blockIdx.z == 0) ? g0 : (blockIdx.z == 1) ? g1 : g2;
  const int K = 512;
  int m0 = blockIdx.x * 64, n0 = blockIdx.y * 64;
  int tid = threadIdx.x, wave = tid >> 6, lane = tid & 63;
  int quad = lane >> 4, l16 = lane & 15;
  __shared__ __align__(16) unsigned short sA[64][72];
  __shared__ __align__(16) unsigned short sBt[64][72];
  f32x4 acc[4] = {{0.f,0.f,0.f,0.f},{0.f,0.f,0.f,0.f},{0.f,0.f,0.f,0.f},{0.f,0.f,0.f,0.f}};
  int lr = tid >> 2, ls = tid & 3;
  for (int kb = 0; kb < K; kb += 64) {
    __syncthreads();
    *(uint4*)&sA[lr][ls * 16]      = *(const uint4*)(g.A  + (size_t)(m0 + lr) * K + kb + ls * 16);
    *(uint4*)&sA[lr][ls * 16 + 8]  = *(const uint4*)(g.A  + (size_t)(m0 + lr) * K + kb + ls * 16 + 8);
    *(uint4*)&sBt[lr][ls * 16]     = *(const uint4*)(g.Wt + (size_t)(n0 + lr) * K + kb + ls * 16);
    *(uint4*)&sBt[lr][ls * 16 + 8] = *(const uint4*)(g.Wt + (size_t)(n0 + lr) * K + kb + ls * 16 + 8);
    __syncthreads();
    for (int ks = 0; ks < 2; ++ks) {
      bf16x8 af = *(const bf16x8*)&sA[wave * 16 + l16][ks * 32 + quad * 8];
      for (int nt = 0; nt < 4; ++nt) {
        bf16x8 bf = *(const bf16x8*)&sBt[nt * 16 + l16][ks * 32 + quad * 8];
        acc[nt] = __builtin_amdgcn_mfma_f32_16x16x32_bf16(af, bf, acc[nt], 0, 0, 0);
      }
    }
  }
  int mbase = m0 + wave * 16 + quad * 4;  // C row = quad*4+reg (m89-verified)
  for (int nt = 0; nt < 4; ++nt) {
    int n = n0 + nt * 16 + l16;
    float bv = g.bias[n];
    for (int r = 0; r < 4; ++r) {
      float v = acc[nt][r] + bv;
      int m = mbase + r;
      if (g.mode == 0) {
        int b = m >> 9, l = m & 511, hh = n >> 6, d = n & 63;
        ((unsigned short*)g.out)[(((size_t)(b * 8 + hh) * 512) + l) * 64 + d] = f2bf(v);
      } else if (g.mode == 1) {
        ((float*)g.out)[(size_t)m * 512 + n] = v;
      } else {
        int b = m >> 9, l = m & 511, hh = n >> 6, d = n & 63;
        ((unsigned short*)g.out)[(((size_t)(b * 8 + hh) * 64) + d) * 512 + l] = f2bf(v);
      }
    }
  }
}

// ---------------- fused edge-bias flash attention, per (b, h, 64-row q-tile) ----------------
__global__ __launch_bounds__(256) void k_attn(
    const unsigned short* __restrict__ Qb, const unsigned short* __restrict__ Kb,
    const unsigned short* __restrict__ Vt, const float* __restrict__ eg,
    const unsigned short* __restrict__ segp,
    const float* __restrict__ wsA, const float* __restrict__ wsC,
    unsigned short* __restrict__ ao) {
  int qt = blockIdx.x, h = blockIdx.y, b = blockIdx.z;
  int bh = b * 8 + h;
  int tid = threadIdx.x, wave = tid >> 6, lane = tid & 63;
  int quad = lane >> 4, l16 = lane & 15;
  __shared__ __align__(16) unsigned short sQ[64][72];
  __shared__ __align__(16) unsigned short sK[32][72];
  __shared__ __align__(16) unsigned short sVt[64][40];   // [d][key] (V pre-transposed in ws)
  __shared__ __align__(16) unsigned short sP[4][16][40]; // per-wave P relayout scratch
  __shared__ float sAh[513], sCh[513];
  for (int i = tid; i < 513; i += 256) { sAh[i] = wsA[i * 8 + h]; sCh[i] = wsC[i * 8 + h]; }
  {
    int row = tid >> 2, s4 = tid & 3;
    const unsigned short* src = Qb + ((size_t)bh * 512 + qt * 64 + row) * 64 + s4 * 16;
    *(uint4*)&sQ[row][s4 * 16]     = *(const uint4*)src;
    *(uint4*)&sQ[row][s4 * 16 + 8] = *(const uint4*)(src + 8);
  }
  __syncthreads();
  // A-operand frags for Q (m=lane&15, k=quad*8+j), hoisted across the key loop
  bf16x8 qf0 = *(const bf16x8*)&sQ[wave * 16 + l16][quad * 8];
  bf16x8 qf1 = *(const bf16x8*)&sQ[wave * 16 + l16][32 + quad * 8];
  float m_run[4], l_run[4];
  f32x4 Oacc[4] = {{0.f,0.f,0.f,0.f},{0.f,0.f,0.f,0.f},{0.f,0.f,0.f,0.f},{0.f,0.f,0.f,0.f}};
  for (int r = 0; r < 4; ++r) { m_run[r] = -3.4e38f; l_run[r] = 0.f; }
  int qrow_g = qt * 64 + wave * 16 + quad * 4;  // + r gives L-row
  for (int kt = 0; kt < 16; ++kt) {
    int key0 = kt * 32;
    __syncthreads();
    {
      int row = tid >> 3, s8 = tid & 7;
      *(uint4*)&sK[row][s8 * 8] = *(const uint4*)(Kb + ((size_t)bh * 512 + key0 + row) * 64 + s8 * 8);
      int d = tid >> 2, s4 = tid & 3;
      *(uint4*)&sVt[d][s4 * 8] = *(const uint4*)(Vt + ((size_t)bh * 64 + d) * 512 + key0 + s4 * 8);
    }
    __syncthreads();
    // S = Q @ K^T : B-operand n=key (lane&15), k=d
    f32x4 S[2];
    for (int half = 0; half < 2; ++half) {
      f32x4 acc = {0.f, 0.f, 0.f, 0.f};
      bf16x8 kf0 = *(const bf16x8*)&sK[half * 16 + l16][quad * 8];
      bf16x8 kf1 = *(const bf16x8*)&sK[half * 16 + l16][32 + quad * 8];
      acc = __builtin_amdgcn_mfma_f32_16x16x32_bf16(qf0, kf0, acc, 0, 0, 0);
      acc = __builtin_amdgcn_mfma_f32_16x16x32_bf16(qf1, kf1, acc, 0, 0, 0);
      S[half] = acc;
    }
    // scale + exact PWL edge bias
    float Sv[2][4];
    int ebase = (b * 512 + qrow_g) * 512 + key0;
    for (int half = 0; half < 2; ++half)
      for (int r = 0; r < 4; ++r) {
        int eidx = ebase + r * 512 + half * 16 + l16;
        float ev = eg[eidx];
        int sg = segp[eidx];
        Sv[half][r] = S[half][r] * 0.125f + sAh[sg] * ev + sCh[sg];
      }
    // online softmax: rows live in 16-lane quad groups
    float alpha[4];
    for (int r = 0; r < 4; ++r) {
      float mx = fmaxf(Sv[0][r], Sv[1][r]);
      for (int off = 1; off < 16; off <<= 1) mx = fmaxf(mx, __shfl_xor(mx, off, 64));
      float mnew = fmaxf(m_run[r], mx);
      alpha[r] = exp2f((m_run[r] - mnew) * LOG2E);
      float p0 = exp2f((Sv[0][r] - mnew) * LOG2E);
      float p1 = exp2f((Sv[1][r] - mnew) * LOG2E);
      Sv[0][r] = p0; Sv[1][r] = p1;
      float ps = p0 + p1;
      for (int off = 1; off < 16; off <<= 1) ps += __shfl_xor(ps, off, 64);
      l_run[r] = l_run[r] * alpha[r] + ps;
      m_run[r] = mnew;
    }
    for (int nt = 0; nt < 4; ++nt)
      for (int r = 0; r < 4; ++r) Oacc[nt][r] *= alpha[r];
    // P: C-layout -> A-layout via LDS round-trip (m120-verified pattern)
    for (int half = 0; half < 2; ++half)
      for (int r = 0; r < 4; ++r)
        sP[wave][quad * 4 + r][half * 16 + l16] = f2bf(Sv[half][r]);
    __syncthreads();
    bf16x8 pf = *(const bf16x8*)&sP[wave][l16][quad * 8];
    for (int nt = 0; nt < 4; ++nt) {
      bf16x8 vf = *(const bf16x8*)&sVt[nt * 16 + l16][quad * 8];
      Oacc[nt] = __builtin_amdgcn_mfma_f32_16x16x32_bf16(pf, vf, Oacc[nt], 0, 0, 0);
    }
  }
  for (int r = 0; r < 4; ++r) l_run[r] = 1.f / l_run[r];
  for (int nt = 0; nt < 4; ++nt)
    for (int r = 0; r < 4; ++r) {
      float v = Oacc[nt][r] * l_run[r];
      ao[((size_t)(b * 512) + qrow_g + r) * 512 + h * 64 + nt * 16 + l16] = f2bf(v);
    }
}

extern "C" void kernel_launch(void* const* d_in, const int* in_sizes, int n_in,
                              void* d_out, int out_size, void* d_ws, size_t ws_size,
                              hipStream_t stream) {
  const float* q   = (const float*)d_in[0];
  const float* kin = (const float*)d_in[1];
  const float* v   = (const float*)d_in[2];
  const float* eg  = (const float*)d_in[3];
  const float* Wq  = (const float*)d_in[4];
  const float* bq  = (const float*)d_in[5];
  const float* Wk  = (const float*)d_in[6];
  const float* bk  = (const float*)d_in[7];
  const float* Wv  = (const float*)d_in[8];
  const float* bv  = (const float*)d_in[9];
  const float* Wo  = (const float*)d_in[10];
  const float* bo  = (const float*)d_in[11];
  const float* We1 = (const float*)d_in[12];
  const float* be1 = (const float*)d_in[13];
  const float* We2 = (const float*)d_in[14];
  const float* be2 = (const float*)d_in[15];
  unsigned short* wsb = (unsigned short*)d_ws;
  float* wsT = (float*)((char*)d_ws + T_B);
  float* wsA = (float*)((char*)d_ws + A_B);
  float* wsC = (float*)((char*)d_ws + C_B);
  unsigned short* segp = (unsigned short*)((char*)d_ws + SEG_B);

  k_convert<<<2560, 256, 0, stream>>>(q, kin, v, Wq, Wk, Wv, Wo, wsb);
  k_prep<<<1, 512, 0, stream>>>(We1, be1, We2, be2, wsT, wsA, wsC);
  k_seg<<<2048, 256, 0, stream>>>(eg, wsT, segp);
  GemmBatch gq{wsb + XQ_OFF, wsb + WQ_OFF, bq, (void*)(wsb + QB_OFF), 0};
  GemmBatch gk{wsb + XK_OFF, wsb + WK_OFF, bk, (void*)(wsb + KB_OFF), 0};
  GemmBatch gv{wsb + XV_OFF, wsb + WV_OFF, bv, (void*)(wsb + VT_OFF), 2};
  k_gemm<<<dim3(16, 8, 3), 256, 0, stream>>>(gq, gk, gv);
  k_attn<<<dim3(8, 8, 2), 256, 0, stream>>>(wsb + QB_OFF, wsb + KB_OFF, wsb + VT_OFF,
                                            eg, segp, wsA, wsC, wsb + AO_OFF);
  GemmBatch go{wsb + AO_OFF, wsb + WO_OFF, bo, d_out, 1};
  k_gemm<<<dim3(16, 8, 1), 256, 0, stream>>>(go, go, go);
}

// Round 2
// 149.854 us; speedup vs baseline: 1.6051x; 1.6051x over previous
//
#include <hip/hip_runtime.h>
#include <hip/hip_bf16.h>

typedef __attribute__((ext_vector_type(8))) short bf16x8;
typedef __attribute__((ext_vector_type(4))) float f32x4;

#define LOG2E 1.44269504088896340736f

// ---- workspace layout ----
// bf16 element offsets
#define XQ_OFF 0
#define XK_OFF 524288
#define XV_OFF 1048576
#define WQ_OFF 1572864
#define WK_OFF 1835008
#define WV_OFF 2097152
#define WO_OFF 2359296
#define QB_OFF 2621440
#define KB_OFF 3145728
#define VT_OFF 3670016
#define AO_OFF 4194304
// byte offsets (fp32 tables / seg indices)
#define T_B   9437184
#define A_B   (T_B + 4096)
#define C_B   (A_B + 20480)
#define SEG_B (C_B + 20480)

__device__ __forceinline__ unsigned short f2bf(float f) {
  union { __hip_bfloat16 h; unsigned short u; } c;
  c.h = __float2bfloat16(f);
  return c.u;
}

// ---------------- fp32 -> bf16 convert; weights transposed [k][n] -> [n][k] ----------------
__global__ __launch_bounds__(256) void k_convert(
    const float* __restrict__ xq, const float* __restrict__ xk, const float* __restrict__ xv,
    const float* __restrict__ wq, const float* __restrict__ wk, const float* __restrict__ wv,
    const float* __restrict__ wo, unsigned short* __restrict__ wsb) {
  int i = blockIdx.x * 256 + threadIdx.x;  // one float4 per thread; 655360 total
  if (i < 393216) {                        // xq/xk/xv plain: 3 x 131072 float4
    int region = i >> 17;
    int off = i & 131071;
    const float* src = (region == 0) ? xq : (region == 1) ? xk : xv;
    float4 v = ((const float4*)src)[off];
    ushort4 o;
    o.x = f2bf(v.x); o.y = f2bf(v.y); o.z = f2bf(v.z); o.w = f2bf(v.w);
    ((ushort4*)wsb)[i] = o;
  } else {                                 // W's transposed: 4 x 65536 float4
    int j = i - 393216;
    int region = j >> 16;
    int off = j & 65535;
    const float* src = (region == 0) ? wq : (region == 1) ? wk : (region == 2) ? wv : wo;
    float4 v = ((const float4*)src)[off];
    int flat = off << 2;
    int k = flat >> 9, n = flat & 511;
    unsigned short* dst = wsb + WQ_OFF + region * 262144;
    dst[(n + 0) * 512 + k] = f2bf(v.x);
    dst[(n + 1) * 512 + k] = f2bf(v.y);
    dst[(n + 2) * 512 + k] = f2bf(v.z);
    dst[(n + 3) * 512 + k] = f2bf(v.w);
  }
}

// ---------------- edge MLP -> exact piecewise-linear tables (parallelized) ----------------
// f_h(e) = sum_k We2[k,h]*relu(e*w1[k]+b1[k]) + be2[h]  is PWL with breakpoints t_k=-b1/w1.
// Sort breakpoints; per segment s in [0,512]: f_h(e) = A[s][h]*e + C[s][h].
__global__ __launch_bounds__(512) void k_prep(
    const float* __restrict__ w1, const float* __restrict__ b1,
    const float* __restrict__ we2, const float* __restrict__ be2,
    float* __restrict__ wsT, float* __restrict__ wsA, float* __restrict__ wsC) {
  __shared__ float sT[512];
  __shared__ int sIdx[512];
  __shared__ float sDA[512][8];   // reused: seg0-reduction buffer, then sorted deltas+scan
  __shared__ float sDC[512][8];
  __shared__ float sA0[8], sC0[8];
  int tid = threadIdx.x;
  float w = w1[tid], bb = b1[tid];
  sT[tid] = (w != 0.f) ? (-bb / w) : -3.4e38f;  // w==0: never a real crossing
  sIdx[tid] = tid;
  // seg-0 contributions (active set = {k : w1[k] < 0}; w==0 contributes const relu(b))
  {
#pragma unroll
    for (int h = 0; h < 8; ++h) {
      float w2 = we2[tid * 8 + h];
      float ra = 0.f, rc = 0.f;
      if (w < 0.f)       { ra = w2 * w; rc = w2 * bb; }
      else if (w == 0.f) { rc = w2 * fmaxf(bb, 0.f); }
      sDA[tid][h] = ra; sDC[tid][h] = rc;
    }
  }
  // bitonic sort of breakpoints (ascending), 512 elems / 512 threads
  for (int size = 2; size <= 512; size <<= 1) {
    for (int stride = size >> 1; stride > 0; stride >>= 1) {
      __syncthreads();
      int i = tid, j = tid ^ stride;
      if (j > i) {
        bool up = ((i & size) == 0);
        float ti = sT[i], tj = sT[j];
        if (up ? (ti > tj) : (ti < tj)) {
          sT[i] = tj; sT[j] = ti;
          int t = sIdx[i]; sIdx[i] = sIdx[j]; sIdx[j] = t;
        }
      }
    }
  }
  // tree-reduce seg0 contributions
  for (int st = 256; st > 0; st >>= 1) {
    __syncthreads();
    if (tid < st) {
#pragma unroll
      for (int h = 0; h < 8; ++h) { sDA[tid][h] += sDA[tid + st][h]; sDC[tid][h] += sDC[tid + st][h]; }
    }
  }
  __syncthreads();
  if (tid < 8) { sA0[tid] = sDA[0][tid]; sC0[tid] = sDC[0][tid] + be2[tid]; }
  __syncthreads();
  // per-sorted-position deltas
  {
    int k = sIdx[tid];
    float wk = w1[k], bk = b1[k];
#pragma unroll
    for (int h = 0; h < 8; ++h) {
      float w2 = we2[k * 8 + h];
      float da = 0.f, dc = 0.f;
      if (wk > 0.f)      { da =  w2 * wk; dc =  w2 * bk; }  // activates crossing upward
      else if (wk < 0.f) { da = -w2 * wk; dc = -w2 * bk; }  // deactivates
      sDA[tid][h] = da; sDC[tid][h] = dc;
    }
  }
  __syncthreads();
  // inclusive Hillis-Steele scan over sorted positions
  for (int off = 1; off < 512; off <<= 1) {
    float ta[8], tc[8];
    bool act = (tid >= off);
    if (act) {
#pragma unroll
      for (int h = 0; h < 8; ++h) { ta[h] = sDA[tid - off][h]; tc[h] = sDC[tid - off][h]; }
    }
    __syncthreads();
    if (act) {
#pragma unroll
      for (int h = 0; h < 8; ++h) { sDA[tid][h] += ta[h]; sDC[tid][h] += tc[h]; }
    }
    __syncthreads();
  }
  wsT[tid] = sT[tid];
  if (tid < 8) { wsA[tid] = sA0[tid]; wsC[tid] = sC0[tid]; }
#pragma unroll
  for (int h = 0; h < 8; ++h) {
    wsA[(tid + 1) * 8 + h] = sA0[h] + sDA[tid][h];
    wsC[(tid + 1) * 8 + h] = sC0[h] + sDC[tid][h];
  }
}

// ---------------- per-edge segment index (shared by all 8 heads) ----------------
__global__ __launch_bounds__(256) void k_seg(const float* __restrict__ eg,
                                             const float* __restrict__ wsT,
                                             unsigned short* __restrict__ segp) {
  __shared__ float sT[512];
  int tid = threadIdx.x;
  sT[tid] = wsT[tid];
  sT[tid + 256] = wsT[tid + 256];
  __syncthreads();
  int i = blockIdx.x * 256 + tid;  // 524288 total
  float ev = eg[i];
  int lo = 0, hi = 512;
  while (lo < hi) {  // count of T[s] < ev (exact at ties: relu(0)=0 both sides)
    int mid = (lo + hi) >> 1;
    if (sT[mid] < ev) lo = mid + 1; else hi = mid;
  }
  segp[i] = (unsigned short)lo;
}

// ---------------- bf16 MFMA GEMM: Y = X @ W + bias, M=1024 N=512 K=512 ----------------
struct GemmBatch {
  const unsigned short* A;   // [M][K] bf16
  const unsigned short* Wt;  // [N][K] bf16 (pre-transposed weight)
  const float* bias;         // [N] fp32
  void* out;
  int mode;  // 0: bf16 [b,h,l,d]; 1: fp32 row-major [m][n]; 2: bf16 [b,h,d,l] (V transposed)
};

__global__ __launch_bounds__(256) void k_gemm(GemmBatch g0, GemmBatch g1, GemmBatch g2) {
  GemmBatch g = (blockIdx.z == 0) ? g0 : (blockIdx.z == 1) ? g1 : g2;
  const int K = 512;
  int m0 = blockIdx.x * 64, n0 = blockIdx.y * 64;
  int tid = threadIdx.x, wave = tid >> 6, lane = tid & 63;
  int quad = lane >> 4, l16 = lane & 15;
  __shared__ __align__(16) unsigned short sA[64][72];
  __shared__ __align__(16) unsigned short sBt[64][72];
  f32x4 acc[4] = {{0.f,0.f,0.f,0.f},{0.f,0.f,0.f,0.f},{0.f,0.f,0.f,0.f},{0.f,0.f,0.f,0.f}};
  int lr = tid >> 2, ls = tid & 3;
  for (int kb = 0; kb < K; kb += 64) {
    __syncthreads();
    *(uint4*)&sA[lr][ls * 16]      = *(const uint4*)(g.A  + (size_t)(m0 + lr) * K + kb + ls * 16);
    *(uint4*)&sA[lr][ls * 16 + 8]  = *(const uint4*)(g.A  + (size_t)(m0 + lr) * K + kb + ls * 16 + 8);
    *(uint4*)&sBt[lr][ls * 16]     = *(const uint4*)(g.Wt + (size_t)(n0 + lr) * K + kb + ls * 16);
    *(uint4*)&sBt[lr][ls * 16 + 8] = *(const uint4*)(g.Wt + (size_t)(n0 + lr) * K + kb + ls * 16 + 8);
    __syncthreads();
    for (int ks = 0; ks < 2; ++ks) {
      bf16x8 af = *(const bf16x8*)&sA[wave * 16 + l16][ks * 32 + quad * 8];
      for (int nt = 0; nt < 4; ++nt) {
        bf16x8 bf = *(const bf16x8*)&sBt[nt * 16 + l16][ks * 32 + quad * 8];
        acc[nt] = __builtin_amdgcn_mfma_f32_16x16x32_bf16(af, bf, acc[nt], 0, 0, 0);
      }
    }
  }
  int mbase = m0 + wave * 16 + quad * 4;  // C row = quad*4+reg (m89-verified)
  for (int nt = 0; nt < 4; ++nt) {
    int n = n0 + nt * 16 + l16;
    float bv = g.bias[n];
    for (int r = 0; r < 4; ++r) {
      float v = acc[nt][r] + bv;
      int m = mbase + r;
      if (g.mode == 0) {
        int b = m >> 9, l = m & 511, hh = n >> 6, d = n & 63;
        ((unsigned short*)g.out)[(((size_t)(b * 8 + hh) * 512) + l) * 64 + d] = f2bf(v);
      } else if (g.mode == 1) {
        ((float*)g.out)[(size_t)m * 512 + n] = v;
      } else {
        int b = m >> 9, l = m & 511, hh = n >> 6, d = n & 63;
        ((unsigned short*)g.out)[(((size_t)(b * 8 + hh) * 64) + d) * 512 + l] = f2bf(v);
      }
    }
  }
}

// ---------------- fused edge-bias attention ----------------
// Grid (32, 8, 2): 16 q-rows per block. 4 waves split the 512 keys (128 each),
// no barriers in the key loop (wave-private LDS for P relayout; direct global
// K/V fragment loads). Per-wave two-pass softmax, then one-barrier LDS combine.
__global__ __launch_bounds__(256) void k_attn(
    const unsigned short* __restrict__ Qb, const unsigned short* __restrict__ Kb,
    const unsigned short* __restrict__ Vt, const float* __restrict__ eg,
    const unsigned short* __restrict__ segp,
    const float* __restrict__ wsA, const float* __restrict__ wsC,
    unsigned short* __restrict__ ao) {
  int qt = blockIdx.x, h = blockIdx.y, b = blockIdx.z;
  int bh = b * 8 + h;
  int q0 = qt * 16;
  int tid = threadIdx.x, wave = tid >> 6, lane = tid & 63;
  int quad = lane >> 4, l16 = lane & 15;
  __shared__ float sAh[513], sCh[513];
  __shared__ __align__(16) unsigned short sP[4][16][36];  // per-wave P relayout scratch
  __shared__ float sO[4][4][16][16];                      // [wave][nt][row][l16]
  __shared__ float sM[4][16], sL[4][16];
  for (int i = tid; i < 513; i += 256) { sAh[i] = wsA[i * 8 + h]; sCh[i] = wsC[i * 8 + h]; }
  // Q A-fragments straight from global (all 4 waves read the same 2 KB; L1/L2 hit)
  const unsigned short* qp = Qb + ((size_t)bh * 512 + q0 + l16) * 64 + quad * 8;
  bf16x8 qf0 = *(const bf16x8*)qp;
  bf16x8 qf1 = *(const bf16x8*)(qp + 32);
  int key_base = wave * 128;
  // ---- S = Q@K^T for the wave's 128-key slice (no barriers) ----
  f32x4 S[4][2];
#pragma unroll
  for (int kt = 0; kt < 4; ++kt) {
    int key0 = key_base + kt * 32;
#pragma unroll
    for (int half = 0; half < 2; ++half) {
      const unsigned short* kp = Kb + ((size_t)bh * 512 + key0 + half * 16 + l16) * 64 + quad * 8;
      bf16x8 kf0 = *(const bf16x8*)kp;
      bf16x8 kf1 = *(const bf16x8*)(kp + 32);
      f32x4 acc = {0.f, 0.f, 0.f, 0.f};
      acc = __builtin_amdgcn_mfma_f32_16x16x32_bf16(qf0, kf0, acc, 0, 0, 0);
      acc = __builtin_amdgcn_mfma_f32_16x16x32_bf16(qf1, kf1, acc, 0, 0, 0);
      S[kt][half] = acc;
    }
  }
  __syncthreads();  // sAh/sCh ready (placed after MFMA issue to overlap)
  // ---- scale + exact PWL edge bias ----
#pragma unroll
  for (int kt = 0; kt < 4; ++kt)
#pragma unroll
    for (int half = 0; half < 2; ++half)
#pragma unroll
      for (int r = 0; r < 4; ++r) {
        int eidx = (b * 512 + q0 + quad * 4 + r) * 512 + key_base + kt * 32 + half * 16 + l16;
        float ev = eg[eidx];
        int sg = segp[eidx];
        S[kt][half][r] = S[kt][half][r] * 0.125f + sAh[sg] * ev + sCh[sg];
      }
  // ---- two-pass softmax on the wave's slice (rows live in 16-lane quads) ----
  float m_w[4], l_w[4];
#pragma unroll
  for (int r = 0; r < 4; ++r) {
    float mx = -3.4e38f;
#pragma unroll
    for (int kt = 0; kt < 4; ++kt) { mx = fmaxf(mx, fmaxf(S[kt][0][r], S[kt][1][r])); }
    for (int off = 1; off < 16; off <<= 1) mx = fmaxf(mx, __shfl_xor(mx, off, 64));
    float s = 0.f;
#pragma unroll
    for (int kt = 0; kt < 4; ++kt)
#pragma unroll
      for (int half = 0; half < 2; ++half) {
        float p = exp2f((S[kt][half][r] - mx) * LOG2E);
        S[kt][half][r] = p; s += p;
      }
    for (int off = 1; off < 16; off <<= 1) s += __shfl_xor(s, off, 64);
    m_w[r] = mx; l_w[r] = s;
  }
  // ---- PV over the slice: P C-layout -> A-layout via wave-private LDS ----
  f32x4 Oacc[4] = {{0.f,0.f,0.f,0.f},{0.f,0.f,0.f,0.f},{0.f,0.f,0.f,0.f},{0.f,0.f,0.f,0.f}};
#pragma unroll
  for (int kt = 0; kt < 4; ++kt) {
    int key0 = key_base + kt * 32;
#pragma unroll
    for (int half = 0; half < 2; ++half)
#pragma unroll
      for (int r = 0; r < 4; ++r)
        sP[wave][quad * 4 + r][half * 16 + l16] = f2bf(S[kt][half][r]);
    __builtin_amdgcn_wave_barrier();  // per-wave DS ops are in-order; fence compiler only
    bf16x8 pf = *(const bf16x8*)&sP[wave][l16][quad * 8];
    __builtin_amdgcn_wave_barrier();
#pragma unroll
    for (int nt = 0; nt < 4; ++nt) {
      bf16x8 vf = *(const bf16x8*)(Vt + ((size_t)bh * 64 + nt * 16 + l16) * 512 + key0 + quad * 8);
      Oacc[nt] = __builtin_amdgcn_mfma_f32_16x16x32_bf16(pf, vf, Oacc[nt], 0, 0, 0);
    }
  }
  // ---- combine the 4 wave-partials (flash rescale) ----
  if (l16 == 0) {
#pragma unroll
    for (int r = 0; r < 4; ++r) { sM[wave][quad * 4 + r] = m_w[r]; sL[wave][quad * 4 + r] = l_w[r]; }
  }
#pragma unroll
  for (int nt = 0; nt < 4; ++nt)
#pragma unroll
    for (int r = 0; r < 4; ++r)
      sO[wave][nt][quad * 4 + r][l16] = Oacc[nt][r];
  __syncthreads();
  // wave w finalizes d-chunk nt=w for all 16 rows
#pragma unroll
  for (int r = 0; r < 4; ++r) {
    int row = quad * 4 + r;
    float M = fmaxf(fmaxf(sM[0][row], sM[1][row]), fmaxf(sM[2][row], sM[3][row]));
    float L = 0.f, Ov = 0.f;
#pragma unroll
    for (int wv = 0; wv < 4; ++wv) {
      float f = exp2f((sM[wv][row] - M) * LOG2E);
      L += f * sL[wv][row];
      Ov += f * sO[wv][wave][row][l16];
    }
    float v = Ov / L;
    ao[((size_t)(b * 512 + q0 + row)) * 512 + h * 64 + wave * 16 + l16] = f2bf(v);
  }
}

extern "C" void kernel_launch(void* const* d_in, const int* in_sizes, int n_in,
                              void* d_out, int out_size, void* d_ws, size_t ws_size,
                              hipStream_t stream) {
  const float* q   = (const float*)d_in[0];
  const float* kin = (const float*)d_in[1];
  const float* v   = (const float*)d_in[2];
  const float* eg  = (const float*)d_in[3];
  const float* Wq  = (const float*)d_in[4];
  const float* bq  = (const float*)d_in[5];
  const float* Wk  = (const float*)d_in[6];
  const float* bk  = (const float*)d_in[7];
  const float* Wv  = (const float*)d_in[8];
  const float* bv  = (const float*)d_in[9];
  const float* Wo  = (const float*)d_in[10];
  const float* bo  = (const float*)d_in[11];
  const float* We1 = (const float*)d_in[12];
  const float* be1 = (const float*)d_in[13];
  const float* We2 = (const float*)d_in[14];
  const float* be2 = (const float*)d_in[15];
  unsigned short* wsb = (unsigned short*)d_ws;
  float* wsT = (float*)((char*)d_ws + T_B);
  float* wsA = (float*)((char*)d_ws + A_B);
  float* wsC = (float*)((char*)d_ws + C_B);
  unsigned short* segp = (unsigned short*)((char*)d_ws + SEG_B);

  k_convert<<<2560, 256, 0, stream>>>(q, kin, v, Wq, Wk, Wv, Wo, wsb);
  k_prep<<<1, 512, 0, stream>>>(We1, be1, We2, be2, wsT, wsA, wsC);
  k_seg<<<2048, 256, 0, stream>>>(eg, wsT, segp);
  GemmBatch gq{wsb + XQ_OFF, wsb + WQ_OFF, bq, (void*)(wsb + QB_OFF), 0};
  GemmBatch gk{wsb + XK_OFF, wsb + WK_OFF, bk, (void*)(wsb + KB_OFF), 0};
  GemmBatch gv{wsb + XV_OFF, wsb + WV_OFF, bv, (void*)(wsb + VT_OFF), 2};
  k_gemm<<<dim3(16, 8, 3), 256, 0, stream>>>(gq, gk, gv);
  k_attn<<<dim3(32, 8, 2), 256, 0, stream>>>(wsb + QB_OFF, wsb + KB_OFF, wsb + VT_OFF,
                                             eg, segp, wsA, wsC, wsb + AO_OFF);
  GemmBatch go{wsb + AO_OFF, wsb + WO_OFF, bo, d_out, 1};
  k_gemm<<<dim3(16, 8, 1), 256, 0, stream>>>(go, go, go);
}

// Round 3
// 141.565 us; speedup vs baseline: 1.6991x; 1.0585x over previous
//
#include <hip/hip_runtime.h>
#include <hip/hip_bf16.h>

typedef __attribute__((ext_vector_type(8))) short bf16x8;
typedef __attribute__((ext_vector_type(4))) float f32x4;

#define LOG2E 1.44269504088896340736f

// ---- workspace layout ----
// bf16 element offsets
#define XQ_OFF 0
#define XK_OFF 524288
#define XV_OFF 1048576
#define WQ_OFF 1572864
#define WK_OFF 1835008
#define WV_OFF 2097152
#define WO_OFF 2359296
#define QB_OFF 2621440
#define KB_OFF 3145728
#define VT_OFF 3670016
#define AO_OFF 4194304
// byte offsets (fp32 tables / seg indices)
#define T_B   9437184
#define A_B   (T_B + 4096)
#define C_B   (A_B + 20480)
#define SEG_B (C_B + 20480)

__device__ __forceinline__ unsigned short f2bf(float f) {
  union { __hip_bfloat16 h; unsigned short u; } c;
  c.h = __float2bfloat16(f);
  return c.u;
}

// ---------------- edge MLP -> exact piecewise-linear tables (parallelized) ----------------
// f_h(e) = sum_k We2[k,h]*relu(e*w1[k]+b1[k]) + be2[h]  is PWL with breakpoints t_k=-b1/w1.
// Sort breakpoints; per segment s in [0,512]: f_h(e) = A[s][h]*e + C[s][h].
__global__ __launch_bounds__(512) void k_prep(
    const float* __restrict__ w1, const float* __restrict__ b1,
    const float* __restrict__ we2, const float* __restrict__ be2,
    float* __restrict__ wsT, float* __restrict__ wsA, float* __restrict__ wsC) {
  __shared__ float sT[512];
  __shared__ int sIdx[512];
  __shared__ float sDA[512][8];   // reused: seg0-reduction buffer, then sorted deltas+scan
  __shared__ float sDC[512][8];
  __shared__ float sA0[8], sC0[8];
  int tid = threadIdx.x;
  float w = w1[tid], bb = b1[tid];
  sT[tid] = (w != 0.f) ? (-bb / w) : -3.4e38f;  // w==0: never a real crossing
  sIdx[tid] = tid;
  // seg-0 contributions (active set = {k : w1[k] < 0}; w==0 contributes const relu(b))
  {
#pragma unroll
    for (int h = 0; h < 8; ++h) {
      float w2 = we2[tid * 8 + h];
      float ra = 0.f, rc = 0.f;
      if (w < 0.f)       { ra = w2 * w; rc = w2 * bb; }
      else if (w == 0.f) { rc = w2 * fmaxf(bb, 0.f); }
      sDA[tid][h] = ra; sDC[tid][h] = rc;
    }
  }
  // bitonic sort of breakpoints (ascending), 512 elems / 512 threads
  for (int size = 2; size <= 512; size <<= 1) {
    for (int stride = size >> 1; stride > 0; stride >>= 1) {
      __syncthreads();
      int i = tid, j = tid ^ stride;
      if (j > i) {
        bool up = ((i & size) == 0);
        float ti = sT[i], tj = sT[j];
        if (up ? (ti > tj) : (ti < tj)) {
          sT[i] = tj; sT[j] = ti;
          int t = sIdx[i]; sIdx[i] = sIdx[j]; sIdx[j] = t;
        }
      }
    }
  }
  // tree-reduce seg0 contributions
  for (int st = 256; st > 0; st >>= 1) {
    __syncthreads();
    if (tid < st) {
#pragma unroll
      for (int h = 0; h < 8; ++h) { sDA[tid][h] += sDA[tid + st][h]; sDC[tid][h] += sDC[tid + st][h]; }
    }
  }
  __syncthreads();
  if (tid < 8) { sA0[tid] = sDA[0][tid]; sC0[tid] = sDC[0][tid] + be2[tid]; }
  __syncthreads();
  // per-sorted-position deltas
  {
    int k = sIdx[tid];
    float wk = w1[k], bk = b1[k];
#pragma unroll
    for (int h = 0; h < 8; ++h) {
      float w2 = we2[k * 8 + h];
      float da = 0.f, dc = 0.f;
      if (wk > 0.f)      { da =  w2 * wk; dc =  w2 * bk; }  // activates crossing upward
      else if (wk < 0.f) { da = -w2 * wk; dc = -w2 * bk; }  // deactivates
      sDA[tid][h] = da; sDC[tid][h] = dc;
    }
  }
  __syncthreads();
  // inclusive Hillis-Steele scan over sorted positions
  for (int off = 1; off < 512; off <<= 1) {
    float ta[8], tc[8];
    bool act = (tid >= off);
    if (act) {
#pragma unroll
      for (int h = 0; h < 8; ++h) { ta[h] = sDA[tid - off][h]; tc[h] = sDC[tid - off][h]; }
    }
    __syncthreads();
    if (act) {
#pragma unroll
      for (int h = 0; h < 8; ++h) { sDA[tid][h] += ta[h]; sDC[tid][h] += tc[h]; }
    }
    __syncthreads();
  }
  wsT[tid] = sT[tid];
  if (tid < 8) { wsA[tid] = sA0[tid]; wsC[tid] = sC0[tid]; }
#pragma unroll
  for (int h = 0; h < 8; ++h) {
    wsA[(tid + 1) * 8 + h] = sA0[h] + sDA[tid][h];
    wsC[(tid + 1) * 8 + h] = sC0[h] + sDC[tid][h];
  }
}

// ---------------- fused pre-pass: weight transpose (LDS-staged) + x convert + seg index ----
// blocks [0,256): weight bf16 transpose via LDS (coalesced both sides)
// blocks [256,1792): x fp32->bf16 plain convert
// blocks [1792,3840): per-edge segment index binary search
__global__ __launch_bounds__(256) void k_pre(
    const float* __restrict__ xq, const float* __restrict__ xk, const float* __restrict__ xv,
    const float* __restrict__ wq, const float* __restrict__ wk, const float* __restrict__ wv,
    const float* __restrict__ wo, const float* __restrict__ eg,
    const float* __restrict__ wsT, unsigned short* __restrict__ wsb,
    unsigned short* __restrict__ segp) {
  __shared__ __align__(16) char smem[64 * 68 * 2];
  int blk = blockIdx.x, tid = threadIdx.x;
  if (blk < 256) {
    // ---- 64x64 tile transpose of one weight matrix: W[k][n] fp32 -> Wt[n][k] bf16 ----
    unsigned short (*sWt)[68] = (unsigned short (*)[68])smem;
    int mat = blk >> 6, tile = blk & 63;
    int k0 = (tile >> 3) * 64, n0 = (tile & 7) * 64;
    const float* src = (mat == 0) ? wq : (mat == 1) ? wk : (mat == 2) ? wv : wo;
    int row = tid >> 2, cq = tid & 3;  // row = local k, 16 n's per thread
    const float4* sp = (const float4*)(src + (size_t)(k0 + row) * 512 + n0 + cq * 16);
#pragma unroll
    for (int j = 0; j < 4; ++j) {
      float4 v = sp[j];
      int nl = cq * 16 + j * 4;
      sWt[nl + 0][row] = f2bf(v.x);
      sWt[nl + 1][row] = f2bf(v.y);
      sWt[nl + 2][row] = f2bf(v.z);
      sWt[nl + 3][row] = f2bf(v.w);
    }
    __syncthreads();
    int n = tid >> 2, kq = tid & 3;
    unsigned short* dst = wsb + WQ_OFF + mat * 262144 + (size_t)(n0 + n) * 512 + k0 + kq * 16;
    *(uint4*)dst       = *(const uint4*)&sWt[n][kq * 16];
    *(uint4*)(dst + 8) = *(const uint4*)&sWt[n][kq * 16 + 8];
  } else if (blk < 1792) {
    // ---- x fp32 -> bf16, one float4 per thread: 3 x 131072 float4 ----
    int i = (blk - 256) * 256 + tid;
    int region = i >> 17;
    int off = i & 131071;
    const float* src = (region == 0) ? xq : (region == 1) ? xk : xv;
    float4 v = ((const float4*)src)[off];
    ushort4 o;
    o.x = f2bf(v.x); o.y = f2bf(v.y); o.z = f2bf(v.z); o.w = f2bf(v.w);
    ((ushort4*)wsb)[i] = o;
  } else {
    // ---- segment index: count of sorted breakpoints < e ----
    float* sT = (float*)smem;
    sT[tid] = wsT[tid];
    sT[tid + 256] = wsT[tid + 256];
    __syncthreads();
    int i = (blk - 1792) * 256 + tid;  // 524288 total
    float ev = eg[i];
    int lo = 0, hi = 512;
    while (lo < hi) {
      int mid = (lo + hi) >> 1;
      if (sT[mid] < ev) lo = mid + 1; else hi = mid;
    }
    segp[i] = (unsigned short)lo;
  }
}

// ---------------- bf16 MFMA GEMM: Y = X @ W + bias, M=1024 N=512 K=512 ----------------
struct GemmBatch {
  const unsigned short* A;   // [M][K] bf16
  const unsigned short* Wt;  // [N][K] bf16 (pre-transposed weight)
  const float* bias;         // [N] fp32
  void* out;
  int mode;  // 0: bf16 [b,h,l,d]; 1: fp32 row-major [m][n]; 2: bf16 [b,h,d,l] (V transposed)
};

__global__ __launch_bounds__(256) void k_gemm(GemmBatch g0, GemmBatch g1, GemmBatch g2) {
  GemmBatch g = (blockIdx.z == 0) ? g0 : (blockIdx.z == 1) ? g1 : g2;
  const int K = 512;
  int m0 = blockIdx.x * 64, n0 = blockIdx.y * 64;
  int tid = threadIdx.x, wave = tid >> 6, lane = tid & 63;
  int quad = lane >> 4, l16 = lane & 15;
  __shared__ __align__(16) unsigned short sA[64][72];
  __shared__ __align__(16) unsigned short sBt[64][72];
  f32x4 acc[4] = {{0.f,0.f,0.f,0.f},{0.f,0.f,0.f,0.f},{0.f,0.f,0.f,0.f},{0.f,0.f,0.f,0.f}};
  int lr = tid >> 2, ls = tid & 3;
  for (int kb = 0; kb < K; kb += 64) {
    __syncthreads();
    *(uint4*)&sA[lr][ls * 16]      = *(const uint4*)(g.A  + (size_t)(m0 + lr) * K + kb + ls * 16);
    *(uint4*)&sA[lr][ls * 16 + 8]  = *(const uint4*)(g.A  + (size_t)(m0 + lr) * K + kb + ls * 16 + 8);
    *(uint4*)&sBt[lr][ls * 16]     = *(const uint4*)(g.Wt + (size_t)(n0 + lr) * K + kb + ls * 16);
    *(uint4*)&sBt[lr][ls * 16 + 8] = *(const uint4*)(g.Wt + (size_t)(n0 + lr) * K + kb + ls * 16 + 8);
    __syncthreads();
    for (int ks = 0; ks < 2; ++ks) {
      bf16x8 af = *(const bf16x8*)&sA[wave * 16 + l16][ks * 32 + quad * 8];
      for (int nt = 0; nt < 4; ++nt) {
        bf16x8 bf = *(const bf16x8*)&sBt[nt * 16 + l16][ks * 32 + quad * 8];
        acc[nt] = __builtin_amdgcn_mfma_f32_16x16x32_bf16(af, bf, acc[nt], 0, 0, 0);
      }
    }
  }
  int mbase = m0 + wave * 16 + quad * 4;  // C row = quad*4+reg (m89-verified)
  for (int nt = 0; nt < 4; ++nt) {
    int n = n0 + nt * 16 + l16;
    float bv = g.bias[n];
    for (int r = 0; r < 4; ++r) {
      float v = acc[nt][r] + bv;
      int m = mbase + r;
      if (g.mode == 0) {
        int b = m >> 9, l = m & 511, hh = n >> 6, d = n & 63;
        ((unsigned short*)g.out)[(((size_t)(b * 8 + hh) * 512) + l) * 64 + d] = f2bf(v);
      } else if (g.mode == 1) {
        ((float*)g.out)[(size_t)m * 512 + n] = v;
      } else {
        int b = m >> 9, l = m & 511, hh = n >> 6, d = n & 63;
        ((unsigned short*)g.out)[(((size_t)(b * 8 + hh) * 64) + d) * 512 + l] = f2bf(v);
      }
    }
  }
}

// ---------------- fused edge-bias attention ----------------
// Grid (32, 8, 2): 16 q-rows per block. 4 waves split the 512 keys (128 each),
// no barriers in the key loop (wave-private LDS for P relayout; direct global
// K/V fragment loads). Per-wave two-pass softmax, then one-barrier LDS combine.
__global__ __launch_bounds__(256) void k_attn(
    const unsigned short* __restrict__ Qb, const unsigned short* __restrict__ Kb,
    const unsigned short* __restrict__ Vt, const float* __restrict__ eg,
    const unsigned short* __restrict__ segp,
    const float* __restrict__ wsA, const float* __restrict__ wsC,
    unsigned short* __restrict__ ao) {
  int qt = blockIdx.x, h = blockIdx.y, b = blockIdx.z;
  int bh = b * 8 + h;
  int q0 = qt * 16;
  int tid = threadIdx.x, wave = tid >> 6, lane = tid & 63;
  int quad = lane >> 4, l16 = lane & 15;
  __shared__ float sAh[513], sCh[513];
  __shared__ __align__(16) unsigned short sP[4][16][36];  // per-wave P relayout scratch
  __shared__ float sO[4][4][16][16];                      // [wave][nt][row][l16]
  __shared__ float sM[4][16], sL[4][16];
  for (int i = tid; i < 513; i += 256) { sAh[i] = wsA[i * 8 + h]; sCh[i] = wsC[i * 8 + h]; }
  // Q A-fragments straight from global (all 4 waves read the same 2 KB; L1/L2 hit)
  const unsigned short* qp = Qb + ((size_t)bh * 512 + q0 + l16) * 64 + quad * 8;
  bf16x8 qf0 = *(const bf16x8*)qp;
  bf16x8 qf1 = *(const bf16x8*)(qp + 32);
  int key_base = wave * 128;
  // ---- S = Q@K^T for the wave's 128-key slice (no barriers) ----
  f32x4 S[4][2];
#pragma unroll
  for (int kt = 0; kt < 4; ++kt) {
    int key0 = key_base + kt * 32;
#pragma unroll
    for (int half = 0; half < 2; ++half) {
      const unsigned short* kp = Kb + ((size_t)bh * 512 + key0 + half * 16 + l16) * 64 + quad * 8;
      bf16x8 kf0 = *(const bf16x8*)kp;
      bf16x8 kf1 = *(const bf16x8*)(kp + 32);
      f32x4 acc = {0.f, 0.f, 0.f, 0.f};
      acc = __builtin_amdgcn_mfma_f32_16x16x32_bf16(qf0, kf0, acc, 0, 0, 0);
      acc = __builtin_amdgcn_mfma_f32_16x16x32_bf16(qf1, kf1, acc, 0, 0, 0);
      S[kt][half] = acc;
    }
  }
  __syncthreads();  // sAh/sCh ready (placed after MFMA issue to overlap)
  // ---- scale + exact PWL edge bias ----
#pragma unroll
  for (int kt = 0; kt < 4; ++kt)
#pragma unroll
    for (int half = 0; half < 2; ++half)
#pragma unroll
      for (int r = 0; r < 4; ++r) {
        int eidx = (b * 512 + q0 + quad * 4 + r) * 512 + key_base + kt * 32 + half * 16 + l16;
        float ev = eg[eidx];
        int sg = segp[eidx];
        S[kt][half][r] = S[kt][half][r] * 0.125f + sAh[sg] * ev + sCh[sg];
      }
  // ---- two-pass softmax on the wave's slice (rows live in 16-lane quads) ----
  float m_w[4], l_w[4];
#pragma unroll
  for (int r = 0; r < 4; ++r) {
    float mx = -3.4e38f;
#pragma unroll
    for (int kt = 0; kt < 4; ++kt) { mx = fmaxf(mx, fmaxf(S[kt][0][r], S[kt][1][r])); }
    for (int off = 1; off < 16; off <<= 1) mx = fmaxf(mx, __shfl_xor(mx, off, 64));
    float s = 0.f;
#pragma unroll
    for (int kt = 0; kt < 4; ++kt)
#pragma unroll
      for (int half = 0; half < 2; ++half) {
        float p = exp2f((S[kt][half][r] - mx) * LOG2E);
        S[kt][half][r] = p; s += p;
      }
    for (int off = 1; off < 16; off <<= 1) s += __shfl_xor(s, off, 64);
    m_w[r] = mx; l_w[r] = s;
  }
  // ---- PV over the slice: P C-layout -> A-layout via wave-private LDS ----
  f32x4 Oacc[4] = {{0.f,0.f,0.f,0.f},{0.f,0.f,0.f,0.f},{0.f,0.f,0.f,0.f},{0.f,0.f,0.f,0.f}};
#pragma unroll
  for (int kt = 0; kt < 4; ++kt) {
    int key0 = key_base + kt * 32;
#pragma unroll
    for (int half = 0; half < 2; ++half)
#pragma unroll
      for (int r = 0; r < 4; ++r)
        sP[wave][quad * 4 + r][half * 16 + l16] = f2bf(S[kt][half][r]);
    __builtin_amdgcn_wave_barrier();  // per-wave DS ops are in-order; fence compiler only
    bf16x8 pf = *(const bf16x8*)&sP[wave][l16][quad * 8];
    __builtin_amdgcn_wave_barrier();
#pragma unroll
    for (int nt = 0; nt < 4; ++nt) {
      bf16x8 vf = *(const bf16x8*)(Vt + ((size_t)bh * 64 + nt * 16 + l16) * 512 + key0 + quad * 8);
      Oacc[nt] = __builtin_amdgcn_mfma_f32_16x16x32_bf16(pf, vf, Oacc[nt], 0, 0, 0);
    }
  }
  // ---- combine the 4 wave-partials (flash rescale) ----
  if (l16 == 0) {
#pragma unroll
    for (int r = 0; r < 4; ++r) { sM[wave][quad * 4 + r] = m_w[r]; sL[wave][quad * 4 + r] = l_w[r]; }
  }
#pragma unroll
  for (int nt = 0; nt < 4; ++nt)
#pragma unroll
    for (int r = 0; r < 4; ++r)
      sO[wave][nt][quad * 4 + r][l16] = Oacc[nt][r];
  __syncthreads();
  // wave w finalizes d-chunk nt=w for all 16 rows
#pragma unroll
  for (int r = 0; r < 4; ++r) {
    int row = quad * 4 + r;
    float M = fmaxf(fmaxf(sM[0][row], sM[1][row]), fmaxf(sM[2][row], sM[3][row]));
    float L = 0.f, Ov = 0.f;
#pragma unroll
    for (int wv = 0; wv < 4; ++wv) {
      float f = exp2f((sM[wv][row] - M) * LOG2E);
      L += f * sL[wv][row];
      Ov += f * sO[wv][wave][row][l16];
    }
    float v = Ov / L;
    ao[((size_t)(b * 512 + q0 + row)) * 512 + h * 64 + wave * 16 + l16] = f2bf(v);
  }
}

extern "C" void kernel_launch(void* const* d_in, const int* in_sizes, int n_in,
                              void* d_out, int out_size, void* d_ws, size_t ws_size,
                              hipStream_t stream) {
  const float* q   = (const float*)d_in[0];
  const float* kin = (const float*)d_in[1];
  const float* v   = (const float*)d_in[2];
  const float* eg  = (const float*)d_in[3];
  const float* Wq  = (const float*)d_in[4];
  const float* bq  = (const float*)d_in[5];
  const float* Wk  = (const float*)d_in[6];
  const float* bk  = (const float*)d_in[7];
  const float* Wv  = (const float*)d_in[8];
  const float* bv  = (const float*)d_in[9];
  const float* Wo  = (const float*)d_in[10];
  const float* bo  = (const float*)d_in[11];
  const float* We1 = (const float*)d_in[12];
  const float* be1 = (const float*)d_in[13];
  const float* We2 = (const float*)d_in[14];
  const float* be2 = (const float*)d_in[15];
  unsigned short* wsb = (unsigned short*)d_ws;
  float* wsT = (float*)((char*)d_ws + T_B);
  float* wsA = (float*)((char*)d_ws + A_B);
  float* wsC = (float*)((char*)d_ws + C_B);
  unsigned short* segp = (unsigned short*)((char*)d_ws + SEG_B);

  k_prep<<<1, 512, 0, stream>>>(We1, be1, We2, be2, wsT, wsA, wsC);
  k_pre<<<3840, 256, 0, stream>>>(q, kin, v, Wq, Wk, Wv, Wo, eg, wsT, wsb, segp);
  GemmBatch gq{wsb + XQ_OFF, wsb + WQ_OFF, bq, (void*)(wsb + QB_OFF), 0};
  GemmBatch gk{wsb + XK_OFF, wsb + WK_OFF, bk, (void*)(wsb + KB_OFF), 0};
  GemmBatch gv{wsb + XV_OFF, wsb + WV_OFF, bv, (void*)(wsb + VT_OFF), 2};
  k_gemm<<<dim3(16, 8, 3), 256, 0, stream>>>(gq, gk, gv);
  k_attn<<<dim3(32, 8, 2), 256, 0, stream>>>(wsb + QB_OFF, wsb + KB_OFF, wsb + VT_OFF,
                                             eg, segp, wsA, wsC, wsb + AO_OFF);
  GemmBatch go{wsb + AO_OFF, wsb + WO_OFF, bo, d_out, 1};
  k_gemm<<<dim3(16, 8, 1), 256, 0, stream>>>(go, go, go);
}